// Round 18
// baseline (131.449 us; speedup 1.0000x reference)
//
#include <hip/hip_runtime.h>

// PerceptronSP: 8000 independent per-pixel MLPs sharing input x.
//   h1 = leaky(x @ W1[p] + b1[p])   [32x25]@[25x128]   f32 VALU, W1 via DMA
//   h2 = leaky(h1 @ W2[p] + b2[p])  [32x128]@[128x128] bf16 MFMA, W2 via DMA
//   y[:,p] = h2 @ W3[p] + b3[p]
// ~650 MB streamed once -> ~100 us floor @ 6.6 TB/s.
//
// R18: W1 now streams through the same global_load_lds counted-vmcnt pipeline
// as W2 (R14 left W1 on register-dest loads: latency-bound at ~25% fair share,
// ~40% of per-pixel time for 16% of bytes). W1 = 3 tiles [8x128] (rows 0-23)
// reusing the 2x4KB buffers; row 24 via pre-issued register loads (no OOB at
// p=7999). Prologue chains into the W2 loop; LDS 19.2 KB -> 8 blocks/CU.
// Every weight byte in flight via DMA from kernel start.

constexpr int DIM_IN = 25;
constexpr int H      = 128;
constexpr int P      = 8000;
constexpr int BS     = 32;
constexpr float NEG  = 0.01f;

typedef short  short4v __attribute__((ext_vector_type(4)));
typedef short  short8v __attribute__((ext_vector_type(8)));
typedef float  f32x16  __attribute__((ext_vector_type(16)));

__device__ __forceinline__ float leaky(float v) { return v >= 0.f ? v : NEG * v; }

__device__ __forceinline__ short bf_rne(float f) {   // f32 -> bf16 bits, RNE
    unsigned u = __builtin_bit_cast(unsigned, f);
    return (short)((u + 0x7fffu + ((u >> 16) & 1u)) >> 16);
}
__device__ __forceinline__ short bf_rna(float f) {   // f32 -> bf16 bits, round-nearest-away
    unsigned u = __builtin_bit_cast(unsigned, f);
    return (short)((u + 0x8000u) >> 16);
}

// ---- staging: 4KB tiles via global_load_lds, 4 x 1KB insts (verified R7+) ----
// W1 tile T8: rows [8*T8, 8*T8+8) x all 128 cols; buf layout [8][128] f32.
#define STAGE_W1(BUF, T8) {                                                    \
    const float* g_ = W1p + (size_t)(8 * (T8)) * H + (t << 2);                 \
    float* d_ = &w12t[BUF][0];                                                 \
    _Pragma("unroll")                                                          \
    for (int i_ = 0; i_ < 4; ++i_)                                             \
        __builtin_amdgcn_global_load_lds(                                      \
            (const __attribute__((address_space(1))) unsigned*)(g_ + i_ * 256),\
            (__attribute__((address_space(3))) unsigned*)(d_ + i_ * 256),      \
            16, 0, 0); }

// W2 tile: rows [16*KT,+16) x cols [64*HF,+64); buf layout [16][64] f32.
#define STAGE_T(BUF, KT, HF) {                                                 \
    const float* g_ = W2p + (size_t)(16 * (KT) + (t >> 4)) * H                 \
                      + 64 * (HF) + ((t & 15) << 2);                           \
    float* d_ = &w12t[BUF][0];                                                 \
    _Pragma("unroll")                                                          \
    for (int i_ = 0; i_ < 4; ++i_)                                             \
        __builtin_amdgcn_global_load_lds(                                      \
            (const __attribute__((address_space(1))) unsigned*)(g_ + (size_t)i_ * 4 * H), \
            (__attribute__((address_space(3))) unsigned*)(d_ + i_ * 256),      \
            16, 0, 0); }

// layer-1 consume of one W1 tile (8 rows) from LDS: per row 2 b128 broadcast
// reads of W + 2 b128 reads of x^T, 64 FMAs into aL1.
#define L1_CONSUME(BUF, T8) {                                                  \
    _Pragma("unroll")                                                          \
    for (int dd_ = 0; dd_ < 8; ++dd_) {                                        \
        const int d_ = 8 * (T8) + dd_;                                         \
        const float4 a0_ = *reinterpret_cast<const float4*>(&sxT[d_][r0]);     \
        const float4 a1_ = *reinterpret_cast<const float4*>(&sxT[d_][r0 + 4]); \
        const float4 wl_ = *reinterpret_cast<const float4*>(&w12t[BUF][dd_ * H + c0]); \
        const float4 wh_ = *reinterpret_cast<const float4*>(&w12t[BUF][dd_ * H + 64 + c0]); \
        const float av_[8] = {a0_.x, a0_.y, a0_.z, a0_.w, a1_.x, a1_.y, a1_.z, a1_.w}; \
        const float wv_[8] = {wl_.x, wl_.y, wl_.z, wl_.w, wh_.x, wh_.y, wh_.z, wh_.w}; \
        _Pragma("unroll")                                                      \
        for (int i_ = 0; i_ < 8; ++i_)                                         \
            _Pragma("unroll")                                                  \
            for (int c_ = 0; c_ < 8; ++c_)                                     \
                aL1[i_][c_] += av_[i_] * wv_[c_];                              \
    } }

// layer-2 consume: one [16k x 64n] tile = one K=16 step of 32x32x16 MFMA
// (mapping verified R8/R12/R14; C/D per guide m74/m101).
#define CONSUME_T(BUF, KT, HF) {                                               \
    const int ao_ = lo * 256 + 32 * (KT) + 16 * hi;                            \
    const short8v a_ = *reinterpret_cast<const short8v*>(                      \
        (const char*)h1b + (ao_ ^ ((lo & 7) << 4)));                           \
    const float* tb_ = &w12t[BUF][hi * 512 + lo];                              \
    _Pragma("unroll")                                                          \
    for (int n2_ = 0; n2_ < 2; ++n2_) {                                        \
        const float* col_ = tb_ + 32 * n2_;                                    \
        short8v bf_;                                                           \
        bf_[0] = bf_rna(col_[0]);   bf_[1] = bf_rna(col_[64]);                 \
        bf_[2] = bf_rna(col_[128]); bf_[3] = bf_rna(col_[192]);                \
        bf_[4] = bf_rna(col_[256]); bf_[5] = bf_rna(col_[320]);                \
        bf_[6] = bf_rna(col_[384]); bf_[7] = bf_rna(col_[448]);                \
        acc[2 * (HF) + n2_] = __builtin_amdgcn_mfma_f32_32x32x16_bf16(         \
            a_, bf_, acc[2 * (HF) + n2_], 0, 0, 0);                            \
    } }

__global__ __launch_bounds__(64, 2) void pixel_mlp_kernel(
    const float* __restrict__ x,    // [BS][DIM_IN]
    const float* __restrict__ W1,   // [P][DIM_IN][H]
    const float* __restrict__ b1,   // [P][H]
    const float* __restrict__ W2,   // [P][H][H]
    const float* __restrict__ b2,   // [P][H]
    const float* __restrict__ W3,   // [P][H]
    const float* __restrict__ b3,   // [P]
    float* __restrict__ y)          // [BS][P]
{
    const int p  = blockIdx.x;
    const int t  = threadIdx.x;     // 0..63, one wave
    const int cc = t & 15;          // layer-1 col group
    const int gg = t >> 4;          // layer-1 row group
    const int c0 = cc << 2;
    const int r0 = gg << 3;
    const int lo = t & 31;          // MFMA row/col lane
    const int hi = t >> 5;          // MFMA k-group

    __shared__ float sxT[DIM_IN][BS];   // 3.2 KB
    __shared__ short h1b[BS][H];        // 8 KB, h1 bf16 bits, XOR-swizzled 16B slots
    __shared__ float w12t[2][16 * 64];  // 8 KB, shared W1/W2 tile double buffer

    const float* W1p = W1 + (size_t)p * (DIM_IN * H);
    const float* W2p = W2 + (size_t)p * (H * H);

    // ---- register loads first (oldest in vmcnt FIFO; retired by 1st wait) ----
    const float4 b1l  = *reinterpret_cast<const float4*>(b1 + (size_t)p * H + c0);
    const float4 b1h  = *reinterpret_cast<const float4*>(b1 + (size_t)p * H + 64 + c0);
    const float4 w24l = *reinterpret_cast<const float4*>(W1p + 24 * H + c0);
    const float4 w24h = *reinterpret_cast<const float4*>(W1p + 24 * H + 64 + c0);
    float b2v[4], w3v[4];
    #pragma unroll
    for (int nb = 0; nb < 4; ++nb) {
        b2v[nb] = b2[(size_t)p * H + 32 * nb + lo];
        w3v[nb] = W3[(size_t)p * H + 32 * nb + lo];
    }
    const float b3s = b3[p];
    asm volatile("" ::: "memory");

    // W1 tiles 0,1 (rows 0-15) in flight
    STAGE_W1(0, 0)
    STAGE_W1(1, 1)
    asm volatile("" ::: "memory");

    // stage x^T (plain LDS stores)
    for (int i = t; i < DIM_IN * BS; i += 64)
        sxT[i >> 5][i & 31] = x[(i & 31) * DIM_IN + (i >> 5)];
    asm volatile("s_waitcnt lgkmcnt(0)" ::: "memory");

    // ---------------- layer 1: h1 = leaky(x @ W1 + b1) ----------------
    float aL1[8][8];
    {
        const float bv[8] = {b1l.x, b1l.y, b1l.z, b1l.w, b1h.x, b1h.y, b1h.z, b1h.w};
        #pragma unroll
        for (int i = 0; i < 8; ++i)
            #pragma unroll
            for (int c = 0; c < 8; ++c)
                aL1[i][c] = bv[c];
    }

    // tile-pipelined: consume W1 t0,t1,t2 while staging t2 then W2 T(0,*)
    asm volatile("s_waitcnt vmcnt(4)" ::: "memory");   // t0 + all reg loads done
    L1_CONSUME(0, 0)
    asm volatile("s_waitcnt lgkmcnt(0)" ::: "memory");
    STAGE_W1(0, 2)                                      // rows 16-23
    asm volatile("s_waitcnt vmcnt(4)" ::: "memory");   // t1 done
    L1_CONSUME(1, 1)
    asm volatile("s_waitcnt lgkmcnt(0)" ::: "memory");
    STAGE_T(1, 0, 0)                                    // W2 (KT0,HF0) -> buf1
    asm volatile("s_waitcnt vmcnt(4)" ::: "memory");   // t2 done
    L1_CONSUME(0, 2)
    {   // row 24 from pre-issued registers
        const float4 a0 = *reinterpret_cast<const float4*>(&sxT[24][r0]);
        const float4 a1 = *reinterpret_cast<const float4*>(&sxT[24][r0 + 4]);
        const float av[8] = {a0.x, a0.y, a0.z, a0.w, a1.x, a1.y, a1.z, a1.w};
        const float wv[8] = {w24l.x, w24l.y, w24l.z, w24l.w,
                             w24h.x, w24h.y, w24h.z, w24h.w};
        #pragma unroll
        for (int i = 0; i < 8; ++i)
            #pragma unroll
            for (int c = 0; c < 8; ++c)
                aL1[i][c] += av[i] * wv[c];
    }
    asm volatile("s_waitcnt lgkmcnt(0)" ::: "memory");
    STAGE_T(0, 0, 1)                                    // W2 (KT0,HF1) -> buf0

    // write h1 (leaky, RNE bf16), XOR-swizzled: byte ^= ((row&7)<<4)
    #pragma unroll
    for (int i = 0; i < 8; ++i) {
        short4v lov, hiv;
        lov[0] = bf_rne(leaky(aL1[i][0])); lov[1] = bf_rne(leaky(aL1[i][1]));
        lov[2] = bf_rne(leaky(aL1[i][2])); lov[3] = bf_rne(leaky(aL1[i][3]));
        hiv[0] = bf_rne(leaky(aL1[i][4])); hiv[1] = bf_rne(leaky(aL1[i][5]));
        hiv[2] = bf_rne(leaky(aL1[i][6])); hiv[3] = bf_rne(leaky(aL1[i][7]));
        const int ro = (r0 + i) * 256;
        const int sz = ((r0 + i) & 7) << 4;
        *reinterpret_cast<short4v*>((char*)h1b + ((ro + 8 * cc) ^ sz))       = lov;
        *reinterpret_cast<short4v*>((char*)h1b + ((ro + 128 + 8 * cc) ^ sz)) = hiv;
    }
    asm volatile("s_waitcnt lgkmcnt(0)" ::: "memory");
    __builtin_amdgcn_sched_barrier(0);

    // ---------------- layer 2: h2 = leaky(h1 @ W2 + b2), 32x32x16 MFMA ----------------
    f32x16 acc[4];
    #pragma unroll
    for (int nb = 0; nb < 4; ++nb)
        acc[nb] = (f32x16)(0.f);

    // 16 tiles: KT 0..7 x HF 0,1; HF0 lives in buf1, HF1 in buf0 (from the
    // prologue staging). 2 tiles (8 insts) in flight; vmcnt(4) = oldest landed.
    #pragma unroll 1
    for (int kt = 0; kt < 7; ++kt) {
        asm volatile("s_waitcnt vmcnt(4)" ::: "memory");
        CONSUME_T(1, kt, 0)
        asm volatile("s_waitcnt lgkmcnt(0)" ::: "memory");
        STAGE_T(1, kt + 1, 0)
        asm volatile("s_waitcnt vmcnt(4)" ::: "memory");
        CONSUME_T(0, kt, 1)
        asm volatile("s_waitcnt lgkmcnt(0)" ::: "memory");
        STAGE_T(0, kt + 1, 1)
    }
    asm volatile("s_waitcnt vmcnt(4)" ::: "memory");
    CONSUME_T(1, 7, 0)
    asm volatile("s_waitcnt vmcnt(0)" ::: "memory");
    CONSUME_T(0, 7, 1)

    // ---------------- layer 3: y = leaky(h2 + b2) @ W3 + b3 ----------------
    // lane (lo,hi) holds D col n = 32*nb + lo, rows r = (reg&3)+8*(reg>>2)+4*hi
    float s[16];
    #pragma unroll
    for (int reg = 0; reg < 16; ++reg) {
        float acc_s = 0.f;
        #pragma unroll
        for (int nb = 0; nb < 4; ++nb)
            acc_s += leaky(acc[nb][reg] + b2v[nb]) * w3v[nb];
        s[reg] = acc_s;
    }
    // reduce across the 32 lo lanes
    #pragma unroll
    for (int m = 16; m >= 1; m >>= 1) {
        #pragma unroll
        for (int reg = 0; reg < 16; ++reg)
            s[reg] += __shfl_xor(s[reg], m);
    }
    if (lo == 0) {
        #pragma unroll
        for (int reg = 0; reg < 16; ++reg) {
            const int r = (reg & 3) + 8 * (reg >> 2) + 4 * hi;
            y[(size_t)r * P + p] = s[reg] + b3s;
        }
    }
}

extern "C" void kernel_launch(void* const* d_in, const int* in_sizes, int n_in,
                              void* d_out, int out_size, void* d_ws, size_t ws_size,
                              hipStream_t stream) {
    const float* x  = (const float*)d_in[0];
    const float* W1 = (const float*)d_in[1];
    const float* b1 = (const float*)d_in[2];
    const float* W2 = (const float*)d_in[3];
    const float* b2 = (const float*)d_in[4];
    const float* W3 = (const float*)d_in[5];
    const float* b3 = (const float*)d_in[6];
    float* y = (float*)d_out;

    pixel_mlp_kernel<<<dim3(P), dim3(64), 0, stream>>>(x, W1, b1, W2, b2, W3, b3, y);
}